// Round 3
// baseline (520.354 us; speedup 1.0000x reference)
//
#include <hip/hip_runtime.h>
#include <hip/hip_bf16.h>

// ---------------- problem constants ----------------
#define Bn 16
#define Tn 256
#define Fn 128
#define Cn 32
#define Dn 32
#define EPSf 1e-5f
#define SELU_L 1.0507009873554805f
#define SELU_A 1.6732632423543772f

typedef unsigned short u16;
typedef unsigned int u32;

struct Ptrs { const void* p[39]; };

// ---------------- param offsets (floats, in ws) ----------------
#define P_C1W 0          // 1024
#define P_C1B 1024       // 32
#define P_MW  1056       // 32  (= c2w*bnA*selu_lambda)
#define P_MK  1088       // 1
#define P_FC  1089       // gat block, 3264 floats
#define P_TCG (1089+3264)
// gat block internal
#define G_APW 0
#define G_APB 1024
#define G_AW  1056
#define G_PWW 1088
#define G_PWB 2112
#define G_POW 2144
#define G_POB 3168
#define G_GS  3200
#define G_GB  3232
#define GAT_SZ 3264
#define P_PFW (P_TCG+GAT_SZ)   // 32
#define P_PFB (P_PFW+32)       // 1
#define P_PTW (P_PFB+1)        // 32
#define P_PTB (P_PTW+32)       // 1
#define P_W1  (P_PTB+1)        // 1024
#define P_W2  (P_W1+1024)      // 1024
#define P_FCW (P_W2+1024)      // 128
#define P_FCB (P_FCW+128)      // 2
#define P_FLAG 10000           // 1.0 if inputs are bf16, 0.0 if fp32

// ---------------- ws layout (floats) ----------------
#define WS_M     10240                    // 524288  (m then M0, in-place)
#define WS_FCATT (WS_M+524288)            // 65536   (B,128,32)
#define WS_TCATT (WS_FCATT+65536)         // 131072  (B,256,32)
#define WS_FCGAT (WS_TCATT+131072)        // 65536
#define WS_TCGAT (WS_FCGAT+65536)         // 131072
#define WS_XF    (WS_TCGAT+131072)        // 32768   (B,64,32)
#define WS_XT    (WS_XF+32768)            // 65536   (B,128,32)
#define WS_XFF   (WS_XT+65536)            // 32768
#define WS_XTF   (WS_XFF+32768)           // 65536

// ---------------- helpers ----------------
__device__ __forceinline__ float bf2f(u16 u) {
    union { u32 i; float f; } v; v.i = ((u32)u) << 16; return v.f;
}
__device__ __forceinline__ u16 f2bf(float f) {
    union { float f; u32 u; } v; v.f = f;
    u32 r = (v.u + 0x7fffu + ((v.u >> 16) & 1u)) >> 16;
    return (u16)r;
}
__device__ __forceinline__ void up2(u32 u, float* o) {
    union { u32 i; float f; } a, b;
    a.i = u << 16; b.i = u & 0xffff0000u;
    o[0] = a.f; o[1] = b.f;
}
__device__ __forceinline__ float tanh_fast(float x) {
    float e = __expf(2.f * x);          // inf for large x, 0 for very negative
    return 1.f - 2.f / (e + 1.f);       // saturates to +-1 correctly
}
// dual-dtype param load
__device__ __forceinline__ float ldp(const void* p, int i, int isb) {
    return isb ? bf2f(((const u16*)p)[i]) : ((const float*)p)[i];
}

// ---------------- K0: detect dtype + convert/fold params ----------------
__global__ void k0_setup(Ptrs in, float* __restrict__ P) {
    __shared__ int sflag;
    int tid = threadIdx.x;
    if (tid == 0) {
        // Sniff dtype of x: decode first 256 u16 as bf16. Genuine bf16 N(0,1)
        // stays |v|<64; fp32 mantissa halves decode insane ~48% of the time.
        const u16* xu = (const u16*)in.p[0];
        int bad = 0;
        for (int i = 0; i < 256; i++) {
            float f = bf2f(xu[i]);
            float a = fabsf(f);
            if (!(a < 64.f) && !(a == 0.f)) bad++;   // counts inf/NaN/huge
        }
        sflag = (bad <= 8) ? 1 : 0;   // 1 => bf16 inputs
        P[P_FLAG] = (float)sflag;
    }
    __syncthreads();
    const int isb = sflag;

    for (int i = tid; i < 1024; i += 256) P[P_C1W + i] = ldp(in.p[1], i, isb);
    if (tid < 32) {
        P[P_C1B + tid] = ldp(in.p[2], tid, isb);
        float A = ldp(in.p[3], tid, isb) * rsqrtf(ldp(in.p[6], tid, isb) + EPSf);
        P[P_MW + tid] = ldp(in.p[7], tid, isb) * A * SELU_L;
    }
    if (tid == 0) {
        float k = ldp(in.p[8], 0, isb);
        for (int o = 0; o < 32; o++) {
            float A = ldp(in.p[3], o, isb) * rsqrtf(ldp(in.p[6], o, isb) + EPSf);
            float Bc = ldp(in.p[4], o, isb) - ldp(in.p[5], o, isb) * A;
            k += ldp(in.p[7], o, isb) * Bc;
        }
        P[P_MK] = k;
    }
    for (int g = 0; g < 2; g++) {
        int ib = g ? 20 : 9;
        float* G = P + (g ? P_TCG : P_FC);
        for (int i = tid; i < 1024; i += 256) {
            G[G_APW + i] = ldp(in.p[ib + 0], i, isb);
            G[G_PWW + i] = ldp(in.p[ib + 3], i, isb);
            G[G_POW + i] = ldp(in.p[ib + 5], i, isb);
        }
        if (tid < 32) {
            G[G_APB + tid] = ldp(in.p[ib + 1], tid, isb);
            G[G_AW  + tid] = ldp(in.p[ib + 2], tid, isb);
            G[G_PWB + tid] = ldp(in.p[ib + 4], tid, isb);
            G[G_POB + tid] = ldp(in.p[ib + 6], tid, isb);
            float gs = ldp(in.p[ib + 7], tid, isb) * rsqrtf(ldp(in.p[ib + 10], tid, isb) + EPSf);
            G[G_GS + tid] = gs;
            G[G_GB + tid] = ldp(in.p[ib + 8], tid, isb) - ldp(in.p[ib + 9], tid, isb) * gs;
        }
    }
    if (tid < 32) {
        P[P_PFW + tid] = ldp(in.p[31], tid, isb);
        P[P_PTW + tid] = ldp(in.p[33], tid, isb);
    }
    if (tid == 0) { P[P_PFB] = ldp(in.p[32], 0, isb); P[P_PTB] = ldp(in.p[34], 0, isb); }
    for (int i = tid; i < 1024; i += 256) {
        P[P_W1 + i] = ldp(in.p[35], i, isb);
        P[P_W2 + i] = ldp(in.p[36], i, isb);
    }
    if (tid < 128) P[P_FCW + tid] = ldp(in.p[37], tid, isb);
    if (tid < 2)   P[P_FCB + tid] = ldp(in.p[38], tid, isb);
}

// ---------------- K1: conv1 + SELU + BN + conv2 -> m ----------------
__global__ __launch_bounds__(256) void k1_conv_m(const void* __restrict__ xin,
                                                 const float* __restrict__ P,
                                                 float* __restrict__ M) {
    int idx = blockIdx.x * 256 + threadIdx.x;          // b*T*F + t*F + f
    const int isb = __builtin_amdgcn_readfirstlane((int)P[P_FLAG]);
    float xv[32];
    if (isb) {
        const uint4* xp4 = reinterpret_cast<const uint4*>((const u16*)xin + (size_t)idx * 32);
        uint4 q0 = xp4[0], q1 = xp4[1], q2 = xp4[2], q3 = xp4[3];
        up2(q0.x, xv + 0);  up2(q0.y, xv + 2);  up2(q0.z, xv + 4);  up2(q0.w, xv + 6);
        up2(q1.x, xv + 8);  up2(q1.y, xv + 10); up2(q1.z, xv + 12); up2(q1.w, xv + 14);
        up2(q2.x, xv + 16); up2(q2.y, xv + 18); up2(q2.z, xv + 20); up2(q2.w, xv + 22);
        up2(q3.x, xv + 24); up2(q3.y, xv + 26); up2(q3.z, xv + 28); up2(q3.w, xv + 30);
    } else {
        const float4* xf4 = reinterpret_cast<const float4*>((const float*)xin + (size_t)idx * 32);
        #pragma unroll
        for (int q = 0; q < 8; q++) {
            float4 v = xf4[q];
            xv[q * 4 + 0] = v.x; xv[q * 4 + 1] = v.y;
            xv[q * 4 + 2] = v.z; xv[q * 4 + 3] = v.w;
        }
    }

    float acc = P[P_MK];
    #pragma unroll
    for (int o = 0; o < 32; o++) {
        float z = P[P_C1B + o];
        #pragma unroll
        for (int c = 0; c < 32; c++) z = fmaf(P[P_C1W + o * 32 + c], xv[c], z);
        float br = (z > 0.f) ? z : SELU_A * (__expf(z) - 1.f);   // selu lambda folded in MW
        acc = fmaf(P[P_MW + o], br, acc);
    }
    M[idx] = acc;
}

// ---------------- K2: softmax over T (axis=1) + zero FCatt ----------------
__global__ __launch_bounds__(256) void k2_softmax(float* __restrict__ M,
                                                  float* __restrict__ FCzero) {
    int gid = blockIdx.x * 256 + threadIdx.x;   // b*F + f, 2048 total
    int b = gid >> 7, f = gid & 127;
    float* col = M + (size_t)b * Tn * Fn + f;
    float mx = -1e30f;
    for (int t = 0; t < Tn; t++) mx = fmaxf(mx, col[t * Fn]);
    float s = 0.f;
    for (int t = 0; t < Tn; t++) {
        float e = __expf(col[t * Fn] - mx);
        s += e; col[t * Fn] = e;
    }
    float inv = 1.f / s;
    for (int t = 0; t < Tn; t++) col[t * Fn] *= inv;
    for (int i = gid; i < Bn * Fn * Cn; i += 2048) FCzero[i] = 0.f;
}

// ---------------- K3: FCatt (atomics over t) + TCatt (LDS reduce over f) ----------------
__global__ __launch_bounds__(256) void k3_att2(const void* __restrict__ xin,
                                               const float* __restrict__ M,
                                               const float* __restrict__ Pflag,
                                               float* __restrict__ FCatt,
                                               float* __restrict__ TCatt) {
    __shared__ float tile[Fn * Cn];   // 4096
    int bt = blockIdx.x;              // b*T + t
    int b = bt >> 8, t = bt & 255;
    int tid = threadIdx.x;
    const float* Mrow = M + (size_t)b * Tn * Fn + (size_t)t * Fn;
    const int isb = __builtin_amdgcn_readfirstlane((int)Pflag[P_FLAG]);
    if (isb) {
        const u16* xr = (const u16*)xin + (size_t)bt * (Fn * Cn);
        #pragma unroll
        for (int pass = 0; pass < 16; pass++) {
            int e = pass * 256 + tid;
            int f = e >> 5, c = e & 31;
            float v = bf2f(xr[e]) * Mrow[f];
            tile[e] = v;
            atomicAdd(&FCatt[((size_t)b * Fn + f) * Cn + c], v);
        }
    } else {
        const float* xr = (const float*)xin + (size_t)bt * (Fn * Cn);
        #pragma unroll
        for (int pass = 0; pass < 16; pass++) {
            int e = pass * 256 + tid;
            int f = e >> 5, c = e & 31;
            float v = xr[e] * Mrow[f];
            tile[e] = v;
            atomicAdd(&FCatt[((size_t)b * Fn + f) * Cn + c], v);
        }
    }
    __syncthreads();
    for (int s = 2048; s >= 32; s >>= 1) {
        for (int e = tid; e < s; e += 256) tile[e] += tile[e + s];
        __syncthreads();
    }
    if (tid < 32) TCatt[((size_t)b * Tn + t) * Cn + tid] = tile[tid];
}

// ---------------- K4: GAT (both branches; block per (b,i)) ----------------
__global__ __launch_bounds__(256) void k4_gat(const float* __restrict__ P,
                                              const float* __restrict__ FCatt,
                                              const float* __restrict__ TCatt,
                                              float* __restrict__ FCgat,
                                              float* __restrict__ TCgat) {
    __shared__ float hs[256 * 33];
    __shared__ float sc[256];
    __shared__ float red[256];
    int bi = blockIdx.x;
    int N, b, i; const float* h; float* out; const float* G;
    if (bi < 2048) { N = 128; b = bi >> 7; i = bi & 127;
        h = FCatt + (size_t)b * 128 * 32; out = FCgat + (size_t)b * 128 * 32; G = P + P_FC; }
    else { bi -= 2048; N = 256; b = bi >> 8; i = bi & 255;
        h = TCatt + (size_t)b * 256 * 32; out = TCgat + (size_t)b * 256 * 32; G = P + P_TCG; }
    int tid = threadIdx.x;
    for (int e = tid; e < N * 32; e += 256) { int j = e >> 5, c = e & 31; hs[j * 33 + c] = h[e]; }
    __syncthreads();
    float hi_[32];
    #pragma unroll
    for (int c = 0; c < 32; c++) hi_[c] = hs[i * 33 + c];

    float score = 0.f;
    if (tid < N) {
        float p[32];
        #pragma unroll
        for (int c = 0; c < 32; c++) p[c] = hi_[c] * hs[tid * 33 + c];
        #pragma unroll
        for (int d = 0; d < 32; d++) {
            float z = G[G_APB + d];
            #pragma unroll
            for (int c = 0; c < 32; c++) z = fmaf(G[G_APW + d * 32 + c], p[c], z);
            score = fmaf(G[G_AW + d], tanh_fast(z), score);
        }
        sc[tid] = score;
    }
    __syncthreads();
    // block softmax over j in [0,N)
    red[tid] = (tid < N) ? sc[tid] : -1e30f;
    __syncthreads();
    for (int s = 128; s > 0; s >>= 1) { if (tid < s) red[tid] = fmaxf(red[tid], red[tid + s]); __syncthreads(); }
    float mx = red[0];
    __syncthreads();
    float e = (tid < N) ? __expf(sc[tid] - mx) : 0.f;
    red[tid] = e;
    __syncthreads();
    for (int s = 128; s > 0; s >>= 1) { if (tid < s) red[tid] += red[tid + s]; __syncthreads(); }
    float inv = 1.f / red[0];
    __syncthreads();
    sc[tid] = e * inv;          // att_j
    __syncthreads();
    // attsum_c = sum_j att_j * h[j][c]
    int jj = tid >> 5, c0 = tid & 31;
    float acc = 0.f;
    for (int j = jj; j < N; j += 8) acc = fmaf(sc[j], hs[j * 33 + c0], acc);
    red[tid] = acc;
    __syncthreads();
    if (tid < 128) red[tid] += red[tid + 128];
    __syncthreads();
    if (tid < 64)  red[tid] += red[tid + 64];
    __syncthreads();
    if (tid < 32)  red[tid] += red[tid + 32];
    __syncthreads();
    if (tid < 32) {
        int d = tid;
        float z = G[G_PWB + d] + G[G_POB + d];
        #pragma unroll
        for (int c = 0; c < 32; c++)
            z = fmaf(G[G_PWW + d * 32 + c], red[c], fmaf(G[G_POW + d * 32 + c], hi_[c], z));
        z = z * G[G_GS + d] + G[G_GB + d];
        z = SELU_L * ((z > 0.f) ? z : SELU_A * (__expf(z) - 1.f));
        out[(size_t)i * 32 + d] = z;
    }
}

// ---------------- K5: top-k pooling (rank-select, matches lax.top_k tie-break) ----------------
__global__ __launch_bounds__(256) void k5_pool(const float* __restrict__ P,
                                               const float* __restrict__ FCgat,
                                               const float* __restrict__ TCgat,
                                               float* __restrict__ XF,
                                               float* __restrict__ XT) {
    __shared__ float s[256];
    int bi = blockIdx.x;
    int N, kn, b, pboff; const float* g; float* xp; const float* pw;
    if (bi < 16) { b = bi; N = 128; kn = 64;
        g = FCgat + (size_t)b * 128 * 32; xp = XF + (size_t)b * 64 * 32; pw = P + P_PFW; pboff = P_PFB; }
    else { b = bi - 16; N = 256; kn = 128;
        g = TCgat + (size_t)b * 256 * 32; xp = XT + (size_t)b * 128 * 32; pw = P + P_PTW; pboff = P_PTB; }
    int tid = threadIdx.x;
    float sv = 0.f;
    if (tid < N) {
        float z = P[pboff];
        #pragma unroll
        for (int d = 0; d < 32; d++) z = fmaf(pw[d], g[(size_t)tid * 32 + d], z);
        sv = 1.f / (1.f + __expf(-z));
        s[tid] = sv;
    }
    __syncthreads();
    if (tid < N) {
        int rank = 0;
        for (int l = 0; l < N; l++) {
            float sl = s[l];
            rank += (sl > sv) || (sl == sv && l < tid);
        }
        if (rank < kn) {
            #pragma unroll
            for (int d = 0; d < 32; d++) xp[(size_t)rank * 32 + d] = g[(size_t)tid * 32 + d] * sv;
        }
    }
}

// ---------------- K6: cross fusion (wave per output row) ----------------
__global__ __launch_bounds__(256) void k6_fuse(const float* __restrict__ P,
                                               const float* __restrict__ XF,
                                               const float* __restrict__ XT,
                                               float* __restrict__ XFF,
                                               float* __restrict__ XTF) {
    int wid = blockIdx.x * 4 + (threadIdx.x >> 6);
    int lane = threadIdx.x & 63;
    if (wid < 1024) {                       // M1 rows: b*64 + i
        int b = wid >> 6, i = wid & 63;
        const float* xf  = XF + ((size_t)b * 64 + i) * 32;
        const float* xtb = XT + (size_t)b * 128 * 32;
        const float* w1 = P + P_W1;
        int d = lane & 31;
        float y = 0.f;
        #pragma unroll
        for (int c = 0; c < 32; c++) y = fmaf(w1[d * 32 + c], xf[c], y);
        float xtr0[32], xtr1[32];
        #pragma unroll
        for (int c = 0; c < 32; c++) {
            xtr0[c] = xtb[(size_t)lane * 32 + c];
            xtr1[c] = xtb[(size_t)(lane + 64) * 32 + c];
        }
        float s0 = 0.f, s1 = 0.f;
        #pragma unroll
        for (int c = 0; c < 32; c++) {
            float yc = __shfl(y, c, 64);
            s0 = fmaf(yc, xtr0[c], s0);
            s1 = fmaf(yc, xtr1[c], s1);
        }
        float mx = fmaxf(s0, s1);
        #pragma unroll
        for (int off = 1; off < 64; off <<= 1) mx = fmaxf(mx, __shfl_xor(mx, off, 64));
        float e0 = __expf(s0 - mx), e1 = __expf(s1 - mx);
        float sm = e0 + e1;
        #pragma unroll
        for (int off = 1; off < 64; off <<= 1) sm += __shfl_xor(sm, off, 64);
        float inv = 1.f / sm;
        float a0 = e0 * inv, a1 = e1 * inv;
        float v[32];
        #pragma unroll
        for (int c = 0; c < 32; c++) v[c] = a0 * xtr0[c] + a1 * xtr1[c];
        #pragma unroll
        for (int off = 1; off < 64; off <<= 1) {
            #pragma unroll
            for (int c = 0; c < 32; c++) v[c] += __shfl_xor(v[c], off, 64);
        }
        if (lane == 0) {
            float* o = XFF + ((size_t)b * 64 + i) * 32;
            #pragma unroll
            for (int c = 0; c < 32; c++) o[c] = xf[c] + v[c];
        }
    } else {                                // M2 rows: b*128 + i
        int r = wid - 1024;
        int b = r >> 7, i = r & 127;
        const float* xt  = XT + ((size_t)b * 128 + i) * 32;
        const float* xfb = XF + (size_t)b * 64 * 32;
        const float* w2 = P + P_W2;
        int d = lane & 31;
        float y = 0.f;
        #pragma unroll
        for (int c = 0; c < 32; c++) y = fmaf(w2[d * 32 + c], xt[c], y);
        float xfr[32];
        #pragma unroll
        for (int c = 0; c < 32; c++) xfr[c] = xfb[(size_t)lane * 32 + c];
        float sc0 = 0.f;
        #pragma unroll
        for (int c = 0; c < 32; c++) sc0 = fmaf(__shfl(y, c, 64), xfr[c], sc0);
        float mx = sc0;
        #pragma unroll
        for (int off = 1; off < 64; off <<= 1) mx = fmaxf(mx, __shfl_xor(mx, off, 64));
        float e = __expf(sc0 - mx);
        float sm = e;
        #pragma unroll
        for (int off = 1; off < 64; off <<= 1) sm += __shfl_xor(sm, off, 64);
        float a = e / sm;
        float v[32];
        #pragma unroll
        for (int c = 0; c < 32; c++) v[c] = a * xfr[c];
        #pragma unroll
        for (int off = 1; off < 64; off <<= 1) {
            #pragma unroll
            for (int c = 0; c < 32; c++) v[c] += __shfl_xor(v[c], off, 64);
        }
        if (lane == 0) {
            float* o = XTF + ((size_t)b * 128 + i) * 32;
            #pragma unroll
            for (int c = 0; c < 32; c++) o[c] = xt[c] + v[c];
        }
    }
}

// ---------------- K7: row-max + final FC (dtype-aware output) ----------------
__global__ __launch_bounds__(64) void k7_out(const float* __restrict__ P,
                                             const float* __restrict__ XFF,
                                             const float* __restrict__ XTF,
                                             void* __restrict__ outp) {
    __shared__ float node[64];
    int b = blockIdx.x, tid = threadIdx.x;
    if (tid < 32) {
        float m = -1e30f;
        for (int r = 0; r < 64; r++) m = fmaxf(m, XFF[((size_t)b * 64 + r) * 32 + tid]);
        node[tid] = m;
    } else {
        int c = tid - 32;
        float m = -1e30f;
        for (int r = 0; r < 128; r++) m = fmaxf(m, XTF[((size_t)b * 128 + r) * 32 + c]);
        node[tid] = m;
    }
    __syncthreads();
    if (tid < 2) {
        float z = P[P_FCB + tid];
        #pragma unroll
        for (int k = 0; k < 64; k++) z = fmaf(P[P_FCW + tid * 64 + k], node[k], z);
        int isb = (int)P[P_FLAG];
        if (isb) ((u16*)outp)[b * 2 + tid] = f2bf(z);
        else     ((float*)outp)[b * 2 + tid] = z;
    }
}

// ---------------- launch ----------------
extern "C" void kernel_launch(void* const* d_in, const int* in_sizes, int n_in,
                              void* d_out, int out_size, void* d_ws, size_t ws_size,
                              hipStream_t stream) {
    (void)in_sizes; (void)n_in; (void)out_size; (void)ws_size;
    float* W = (float*)d_ws;
    Ptrs ptrs;
    for (int i = 0; i < 39; i++) ptrs.p[i] = d_in[i];
    const void* x = d_in[0];
    float* P = W;

    k0_setup<<<1, 256, 0, stream>>>(ptrs, P);
    k1_conv_m<<<2048, 256, 0, stream>>>(x, P, W + WS_M);
    k2_softmax<<<8, 256, 0, stream>>>(W + WS_M, W + WS_FCATT);
    k3_att2<<<4096, 256, 0, stream>>>(x, W + WS_M, P, W + WS_FCATT, W + WS_TCATT);
    k4_gat<<<6144, 256, 0, stream>>>(P, W + WS_FCATT, W + WS_TCATT, W + WS_FCGAT, W + WS_TCGAT);
    k5_pool<<<32, 256, 0, stream>>>(P, W + WS_FCGAT, W + WS_TCGAT, W + WS_XF, W + WS_XT);
    k6_fuse<<<768, 256, 0, stream>>>(P, W + WS_XF, W + WS_XT, W + WS_XFF, W + WS_XTF);
    k7_out<<<16, 64, 0, stream>>>(P, W + WS_XFF, W + WS_XTF, d_out);
}

// Round 4
// 353.389 us; speedup vs baseline: 1.4725x; 1.4725x over previous
//
#include <hip/hip_runtime.h>
#include <hip/hip_bf16.h>

// ---------------- problem constants ----------------
#define Bn 16
#define Tn 256
#define Fn 128
#define Cn 32
#define Dn 32
#define EPSf 1e-5f
#define SELU_L 1.0507009873554805f
#define SELU_A 1.6732632423543772f

typedef unsigned short u16;
typedef unsigned int u32;

struct Ptrs { const void* p[39]; };

// ---------------- param offsets (floats, in ws) ----------------
#define P_C1W 0          // 1024
#define P_C1B 1024       // 32
#define P_MW  1056       // 32  (= c2w*bnA*selu_lambda)
#define P_MK  1088       // 1
#define P_FC  1089       // gat block, 3264 floats
#define P_TCG (1089+3264)
// gat block internal
#define G_APW 0
#define G_APB 1024
#define G_AW  1056
#define G_PWW 1088
#define G_PWB 2112
#define G_POW 2144
#define G_POB 3168
#define G_GS  3200
#define G_GB  3232
#define GAT_SZ 3264
#define P_PFW (P_TCG+GAT_SZ)   // 32
#define P_PFB (P_PFW+32)       // 1
#define P_PTW (P_PFB+1)        // 32
#define P_PTB (P_PTW+32)       // 1
#define P_W1  (P_PTB+1)        // 1024
#define P_W2  (P_W1+1024)      // 1024
#define P_FCW (P_W2+1024)      // 128
#define P_FCB (P_FCW+128)      // 2
#define P_FLAG 10000           // 1.0 if inputs are bf16, 0.0 if fp32

// ---------------- ws layout (floats) ----------------
#define WS_M     10240                    // 524288  (m then M0; DEAD after k3 -> STC overlays)
#define WS_FCATT (WS_M+524288)            // 65536   (B,128,32)
#define WS_TCATT (WS_FCATT+65536)         // 131072  (B,256,32)
#define WS_FCGAT (WS_TCATT+131072)        // 65536
#define WS_TCGAT (WS_FCGAT+65536)         // 131072
#define WS_XF    (WS_TCGAT+131072)        // 32768   (B,64,32)   SFC overlays XF..XFF until k5
#define WS_XT    (WS_XF+32768)            // 65536   (B,128,32)
#define WS_XFF   (WS_XT+65536)            // 32768
#define WS_XTF   (WS_XFF+32768)           // 65536
// score matrices (bf16), overlaid on dead regions:
//   STC: 16*256*256 u16 = 2 MB  -> overlays WS_M (M consumed by k3)
//   SFC: 16*128*128 u16 = 512KB -> overlays WS_XF..WS_XFF (written only from k5 on)

// ---------------- helpers ----------------
__device__ __forceinline__ float bf2f(u16 u) {
    union { u32 i; float f; } v; v.i = ((u32)u) << 16; return v.f;
}
__device__ __forceinline__ u16 f2bf(float f) {
    union { float f; u32 u; } v; v.f = f;
    u32 r = (v.u + 0x7fffu + ((v.u >> 16) & 1u)) >> 16;
    return (u16)r;
}
__device__ __forceinline__ void up2(u32 u, float* o) {
    union { u32 i; float f; } a, b;
    a.i = u << 16; b.i = u & 0xffff0000u;
    o[0] = a.f; o[1] = b.f;
}
__device__ __forceinline__ float tanh_fast(float x) {
    float e = __expf(2.f * x);
    return 1.f - 2.f / (e + 1.f);
}
__device__ __forceinline__ float ldp(const void* p, int i, int isb) {
    return isb ? bf2f(((const u16*)p)[i]) : ((const float*)p)[i];
}

// ---------------- K0: detect dtype + convert/fold params ----------------
__global__ void k0_setup(Ptrs in, float* __restrict__ P) {
    __shared__ int sflag;
    int tid = threadIdx.x;
    if (tid == 0) {
        const u16* xu = (const u16*)in.p[0];
        int bad = 0;
        for (int i = 0; i < 256; i++) {
            float f = bf2f(xu[i]);
            float a = fabsf(f);
            if (!(a < 64.f) && !(a == 0.f)) bad++;
        }
        sflag = (bad <= 8) ? 1 : 0;
        P[P_FLAG] = (float)sflag;
    }
    __syncthreads();
    const int isb = sflag;

    for (int i = tid; i < 1024; i += 256) P[P_C1W + i] = ldp(in.p[1], i, isb);
    if (tid < 32) {
        P[P_C1B + tid] = ldp(in.p[2], tid, isb);
        float A = ldp(in.p[3], tid, isb) * rsqrtf(ldp(in.p[6], tid, isb) + EPSf);
        P[P_MW + tid] = ldp(in.p[7], tid, isb) * A * SELU_L;
    }
    if (tid == 0) {
        float k = ldp(in.p[8], 0, isb);
        for (int o = 0; o < 32; o++) {
            float A = ldp(in.p[3], o, isb) * rsqrtf(ldp(in.p[6], o, isb) + EPSf);
            float Bc = ldp(in.p[4], o, isb) - ldp(in.p[5], o, isb) * A;
            k += ldp(in.p[7], o, isb) * Bc;
        }
        P[P_MK] = k;
    }
    for (int g = 0; g < 2; g++) {
        int ib = g ? 20 : 9;
        float* G = P + (g ? P_TCG : P_FC);
        for (int i = tid; i < 1024; i += 256) {
            G[G_APW + i] = ldp(in.p[ib + 0], i, isb);
            G[G_PWW + i] = ldp(in.p[ib + 3], i, isb);
            G[G_POW + i] = ldp(in.p[ib + 5], i, isb);
        }
        if (tid < 32) {
            G[G_APB + tid] = ldp(in.p[ib + 1], tid, isb);
            G[G_AW  + tid] = ldp(in.p[ib + 2], tid, isb);
            G[G_PWB + tid] = ldp(in.p[ib + 4], tid, isb);
            G[G_POB + tid] = ldp(in.p[ib + 6], tid, isb);
            float gs = ldp(in.p[ib + 7], tid, isb) * rsqrtf(ldp(in.p[ib + 10], tid, isb) + EPSf);
            G[G_GS + tid] = gs;
            G[G_GB + tid] = ldp(in.p[ib + 8], tid, isb) - ldp(in.p[ib + 9], tid, isb) * gs;
        }
    }
    if (tid < 32) {
        P[P_PFW + tid] = ldp(in.p[31], tid, isb);
        P[P_PTW + tid] = ldp(in.p[33], tid, isb);
    }
    if (tid == 0) { P[P_PFB] = ldp(in.p[32], 0, isb); P[P_PTB] = ldp(in.p[34], 0, isb); }
    for (int i = tid; i < 1024; i += 256) {
        P[P_W1 + i] = ldp(in.p[35], i, isb);
        P[P_W2 + i] = ldp(in.p[36], i, isb);
    }
    if (tid < 128) P[P_FCW + tid] = ldp(in.p[37], tid, isb);
    if (tid < 2)   P[P_FCB + tid] = ldp(in.p[38], tid, isb);
}

// ---------------- K1: conv1 + SELU + BN + conv2 -> m ----------------
__global__ __launch_bounds__(256) void k1_conv_m(const void* __restrict__ xin,
                                                 const float* __restrict__ P,
                                                 float* __restrict__ M) {
    int idx = blockIdx.x * 256 + threadIdx.x;          // b*T*F + t*F + f
    const int isb = __builtin_amdgcn_readfirstlane((int)P[P_FLAG]);
    float xv[32];
    if (isb) {
        const uint4* xp4 = reinterpret_cast<const uint4*>((const u16*)xin + (size_t)idx * 32);
        uint4 q0 = xp4[0], q1 = xp4[1], q2 = xp4[2], q3 = xp4[3];
        up2(q0.x, xv + 0);  up2(q0.y, xv + 2);  up2(q0.z, xv + 4);  up2(q0.w, xv + 6);
        up2(q1.x, xv + 8);  up2(q1.y, xv + 10); up2(q1.z, xv + 12); up2(q1.w, xv + 14);
        up2(q2.x, xv + 16); up2(q2.y, xv + 18); up2(q2.z, xv + 20); up2(q2.w, xv + 22);
        up2(q3.x, xv + 24); up2(q3.y, xv + 26); up2(q3.z, xv + 28); up2(q3.w, xv + 30);
    } else {
        const float4* xf4 = reinterpret_cast<const float4*>((const float*)xin + (size_t)idx * 32);
        #pragma unroll
        for (int q = 0; q < 8; q++) {
            float4 v = xf4[q];
            xv[q * 4 + 0] = v.x; xv[q * 4 + 1] = v.y;
            xv[q * 4 + 2] = v.z; xv[q * 4 + 3] = v.w;
        }
    }
    float acc = P[P_MK];
    #pragma unroll
    for (int o = 0; o < 32; o++) {
        float z = P[P_C1B + o];
        #pragma unroll
        for (int c = 0; c < 32; c++) z = fmaf(P[P_C1W + o * 32 + c], xv[c], z);
        float br = (z > 0.f) ? z : SELU_A * (__expf(z) - 1.f);
        acc = fmaf(P[P_MW + o], br, acc);
    }
    M[idx] = acc;
}

// ---------------- K2: softmax over T + zero FCatt (128 blocks) ----------------
__global__ __launch_bounds__(256) void k2_softmax(float* __restrict__ M,
                                                  float* __restrict__ FCzero) {
    __shared__ float r[256];
    int b = blockIdx.x >> 3, fg = blockIdx.x & 7;
    int tid = threadIdx.x;
    int fl = tid & 15, ts = tid >> 4;         // 16 f x 16 t-slices
    float* col = M + (size_t)b * (Tn * Fn) + fg * 16 + fl;
    float v[16];
    float mx = -1e30f;
    #pragma unroll
    for (int k = 0; k < 16; k++) { v[k] = col[(ts * 16 + k) * Fn]; mx = fmaxf(mx, v[k]); }
    r[tid] = mx; __syncthreads();
    for (int s = 128; s >= 16; s >>= 1) { if (tid < s) r[tid] = fmaxf(r[tid], r[tid + s]); __syncthreads(); }
    mx = r[fl];
    __syncthreads();
    float sm = 0.f;
    #pragma unroll
    for (int k = 0; k < 16; k++) { v[k] = __expf(v[k] - mx); sm += v[k]; }
    r[tid] = sm; __syncthreads();
    for (int s = 128; s >= 16; s >>= 1) { if (tid < s) r[tid] += r[tid + s]; __syncthreads(); }
    float inv = 1.f / r[fl];
    #pragma unroll
    for (int k = 0; k < 16; k++) col[(ts * 16 + k) * Fn] = v[k] * inv;
    int gid = blockIdx.x * 256 + tid;
    for (int i = gid; i < Bn * Fn * Cn; i += 128 * 256) FCzero[i] = 0.f;
}

// ---------------- K3: FCatt (register partials, few atomics) + TCatt ----------------
__global__ __launch_bounds__(256) void k3n(const void* __restrict__ xin,
                                           const float* __restrict__ M,
                                           const float* __restrict__ Pflag,
                                           float* __restrict__ FCatt,
                                           float* __restrict__ TCatt) {
    __shared__ float lA[256], lB[256];
    int bi = blockIdx.x;                 // 512 blocks: b*32 + tg (8 t's each)
    int b = bi >> 5, tg = bi & 31;
    int tid = threadIdx.x;
    const int isb = __builtin_amdgcn_readfirstlane((int)Pflag[P_FLAG]);
    float fa0[8], fa1[8];
    #pragma unroll
    for (int k = 0; k < 8; k++) { fa0[k] = 0.f; fa1[k] = 0.f; }
    int fbase = tid >> 4;                // thread's f for chunk k: fbase + 16*k
    for (int tt = 0; tt < 8; tt++) {
        int t = tg * 8 + tt;
        const float* Mrow = M + (size_t)b * (Tn * Fn) + (size_t)t * Fn;
        size_t rowoff = ((size_t)b * Tn + t) * (Fn * Cn);
        float ts0 = 0.f, ts1 = 0.f;
        #pragma unroll
        for (int k = 0; k < 8; k++) {
            float x0, x1;
            if (isb) {
                u32 u = *(const u32*)((const u16*)xin + rowoff + tid * 2 + 512 * k);
                float tmp[2]; up2(u, tmp); x0 = tmp[0]; x1 = tmp[1];
            } else {
                float2 v2 = *(const float2*)((const float*)xin + rowoff + tid * 2 + 512 * k);
                x0 = v2.x; x1 = v2.y;
            }
            float m = Mrow[fbase + 16 * k];
            x0 *= m; x1 *= m;
            fa0[k] += x0; fa1[k] += x1;
            ts0 += x0; ts1 += x1;
        }
        lA[tid] = ts0; lB[tid] = ts1;
        __syncthreads();
        if (tid < 32) {
            int half = tid & 1, p = tid >> 1;
            float s = 0.f;
            if (half) { for (int g = 0; g < 16; g++) s += lB[g * 16 + p]; }
            else      { for (int g = 0; g < 16; g++) s += lA[g * 16 + p]; }
            TCatt[((size_t)b * Tn + t) * Cn + tid] = s;
        }
        __syncthreads();
    }
    #pragma unroll
    for (int k = 0; k < 8; k++) {
        atomicAdd(&FCatt[(size_t)b * 4096 + tid * 2 + 512 * k],     fa0[k]);
        atomicAdd(&FCatt[(size_t)b * 4096 + tid * 2 + 512 * k + 1], fa1[k]);
    }
}

// ---------------- K4a: symmetric score tiles -> S (bf16) ----------------
__global__ __launch_bounds__(256) void k4a_scores(const float* __restrict__ P,
                                                  const float* __restrict__ FCatt,
                                                  const float* __restrict__ TCatt,
                                                  u16* __restrict__ SFC,
                                                  u16* __restrict__ STC) {
    __shared__ float li[16 * 33], lj[16 * 33];
    int bi = blockIdx.x;
    int N, nt, b, pr; const float* h; u16* S; const float* G;
    if (bi < 16 * 36) { b = bi / 36; pr = bi % 36; N = 128; nt = 8;
        h = FCatt + (size_t)b * 4096; S = SFC + (size_t)b * 16384; G = P + P_FC; }
    else { bi -= 16 * 36; b = bi / 136; pr = bi % 136; N = 256; nt = 16;
        h = TCatt + (size_t)b * 8192; S = STC + (size_t)b * 65536; G = P + P_TCG; }
    int ti = 0, rem = pr;
    while (rem >= nt - ti) { rem -= nt - ti; ti++; }
    int tj = ti + rem;
    int tid = threadIdx.x;
    for (int e = tid; e < 512; e += 256) {
        int rr = e >> 5, c = e & 31;
        li[rr * 33 + c] = h[(ti * 16 + rr) * 32 + c];
        lj[rr * 33 + c] = h[(tj * 16 + rr) * 32 + c];
    }
    __syncthreads();
    int il = tid >> 4, jl = tid & 15;
    float p[32];
    #pragma unroll
    for (int c = 0; c < 32; c++) p[c] = li[il * 33 + c] * lj[jl * 33 + c];
    float score = 0.f;
    #pragma unroll
    for (int d = 0; d < 32; d++) {
        float z = G[G_APB + d];
        #pragma unroll
        for (int c = 0; c < 32; c++) z = fmaf(G[G_APW + d * 32 + c], p[c], z);
        score = fmaf(G[G_AW + d], tanh_fast(z), score);
    }
    int i = ti * 16 + il, j = tj * 16 + jl;
    u16 sb = f2bf(score);
    S[(size_t)i * N + j] = sb;
    if (ti != tj) S[(size_t)j * N + i] = sb;   // symmetry
}

// ---------------- K4b: softmax over j + attsum + output transform ----------------
__global__ __launch_bounds__(256) void k4b_soft(const float* __restrict__ P,
                                                const float* __restrict__ FCatt,
                                                const float* __restrict__ TCatt,
                                                const u16* __restrict__ SFC,
                                                const u16* __restrict__ STC,
                                                float* __restrict__ FCgat,
                                                float* __restrict__ TCgat) {
    __shared__ float hs[256 * 33];
    __shared__ float sc[256];
    __shared__ float red[256];
    int bi = blockIdx.x;
    int N, b, i; const float* h; float* out; const float* G; const u16* Srow;
    if (bi < 2048) { N = 128; b = bi >> 7; i = bi & 127;
        h = FCatt + (size_t)b * 4096; out = FCgat + (size_t)b * 4096; G = P + P_FC;
        Srow = SFC + (size_t)b * 16384 + (size_t)i * 128; }
    else { bi -= 2048; N = 256; b = bi >> 8; i = bi & 255;
        h = TCatt + (size_t)b * 8192; out = TCgat + (size_t)b * 8192; G = P + P_TCG;
        Srow = STC + (size_t)b * 65536 + (size_t)i * 256; }
    int tid = threadIdx.x;
    for (int e = tid; e < N * 32; e += 256) { int j = e >> 5, c = e & 31; hs[j * 33 + c] = h[e]; }
    if (tid < N) sc[tid] = bf2f(Srow[tid]);
    __syncthreads();
    // softmax over j
    red[tid] = (tid < N) ? sc[tid] : -1e30f;
    __syncthreads();
    for (int s = 128; s > 0; s >>= 1) { if (tid < s) red[tid] = fmaxf(red[tid], red[tid + s]); __syncthreads(); }
    float mx = red[0];
    __syncthreads();
    float e = (tid < N) ? __expf(sc[tid] - mx) : 0.f;
    red[tid] = e;
    __syncthreads();
    for (int s = 128; s > 0; s >>= 1) { if (tid < s) red[tid] += red[tid + s]; __syncthreads(); }
    float inv = 1.f / red[0];
    __syncthreads();
    sc[tid] = e * inv;
    __syncthreads();
    // attsum_c = sum_j att_j * h[j][c]
    int jj = tid >> 5, c0 = tid & 31;
    float acc = 0.f;
    for (int j = jj; j < N; j += 8) acc = fmaf(sc[j], hs[j * 33 + c0], acc);
    red[tid] = acc;
    __syncthreads();
    if (tid < 128) red[tid] += red[tid + 128];
    __syncthreads();
    if (tid < 64)  red[tid] += red[tid + 64];
    __syncthreads();
    if (tid < 32)  red[tid] += red[tid + 32];
    __syncthreads();
    if (tid < 32) {
        int d = tid;
        float z = G[G_PWB + d] + G[G_POB + d];
        #pragma unroll
        for (int c = 0; c < 32; c++)
            z = fmaf(G[G_PWW + d * 32 + c], red[c], fmaf(G[G_POW + d * 32 + c], hs[i * 33 + c], z));
        z = z * G[G_GS + d] + G[G_GB + d];
        z = SELU_L * ((z > 0.f) ? z : SELU_A * (__expf(z) - 1.f));
        out[(size_t)i * 32 + d] = z;
    }
}

// ---------------- K5: top-k pooling (rank-select) ----------------
__global__ __launch_bounds__(256) void k5_pool(const float* __restrict__ P,
                                               const float* __restrict__ FCgat,
                                               const float* __restrict__ TCgat,
                                               float* __restrict__ XF,
                                               float* __restrict__ XT) {
    __shared__ float s[256];
    int bi = blockIdx.x;
    int N, kn, b, pboff; const float* g; float* xp; const float* pw;
    if (bi < 16) { b = bi; N = 128; kn = 64;
        g = FCgat + (size_t)b * 4096; xp = XF + (size_t)b * 2048; pw = P + P_PFW; pboff = P_PFB; }
    else { b = bi - 16; N = 256; kn = 128;
        g = TCgat + (size_t)b * 8192; xp = XT + (size_t)b * 4096; pw = P + P_PTW; pboff = P_PTB; }
    int tid = threadIdx.x;
    float sv = 0.f;
    if (tid < N) {
        float z = P[pboff];
        #pragma unroll
        for (int d = 0; d < 32; d++) z = fmaf(pw[d], g[(size_t)tid * 32 + d], z);
        sv = 1.f / (1.f + __expf(-z));
        s[tid] = sv;
    }
    __syncthreads();
    if (tid < N) {
        int rank = 0;
        for (int l = 0; l < N; l++) {
            float sl = s[l];
            rank += (sl > sv) || (sl == sv && l < tid);
        }
        if (rank < kn) {
            #pragma unroll
            for (int d = 0; d < 32; d++) xp[(size_t)rank * 32 + d] = g[(size_t)tid * 32 + d] * sv;
        }
    }
}

// ---------------- K6: cross fusion (wave per output row) ----------------
__global__ __launch_bounds__(256) void k6_fuse(const float* __restrict__ P,
                                               const float* __restrict__ XF,
                                               const float* __restrict__ XT,
                                               float* __restrict__ XFF,
                                               float* __restrict__ XTF) {
    int wid = blockIdx.x * 4 + (threadIdx.x >> 6);
    int lane = threadIdx.x & 63;
    if (wid < 1024) {                       // M1 rows: b*64 + i
        int b = wid >> 6, i = wid & 63;
        const float* xf  = XF + ((size_t)b * 64 + i) * 32;
        const float* xtb = XT + (size_t)b * 4096;
        const float* w1 = P + P_W1;
        int d = lane & 31;
        float y = 0.f;
        #pragma unroll
        for (int c = 0; c < 32; c++) y = fmaf(w1[d * 32 + c], xf[c], y);
        float xtr0[32], xtr1[32];
        #pragma unroll
        for (int c = 0; c < 32; c++) {
            xtr0[c] = xtb[(size_t)lane * 32 + c];
            xtr1[c] = xtb[(size_t)(lane + 64) * 32 + c];
        }
        float s0 = 0.f, s1 = 0.f;
        #pragma unroll
        for (int c = 0; c < 32; c++) {
            float yc = __shfl(y, c, 64);
            s0 = fmaf(yc, xtr0[c], s0);
            s1 = fmaf(yc, xtr1[c], s1);
        }
        float mx = fmaxf(s0, s1);
        #pragma unroll
        for (int off = 1; off < 64; off <<= 1) mx = fmaxf(mx, __shfl_xor(mx, off, 64));
        float e0 = __expf(s0 - mx), e1 = __expf(s1 - mx);
        float sm = e0 + e1;
        #pragma unroll
        for (int off = 1; off < 64; off <<= 1) sm += __shfl_xor(sm, off, 64);
        float inv = 1.f / sm;
        float a0 = e0 * inv, a1 = e1 * inv;
        float v[32];
        #pragma unroll
        for (int c = 0; c < 32; c++) v[c] = a0 * xtr0[c] + a1 * xtr1[c];
        #pragma unroll
        for (int off = 1; off < 64; off <<= 1) {
            #pragma unroll
            for (int c = 0; c < 32; c++) v[c] += __shfl_xor(v[c], off, 64);
        }
        if (lane == 0) {
            float* o = XFF + ((size_t)b * 64 + i) * 32;
            #pragma unroll
            for (int c = 0; c < 32; c++) o[c] = xf[c] + v[c];
        }
    } else {                                // M2 rows: b*128 + i
        int r = wid - 1024;
        int b = r >> 7, i = r & 127;
        const float* xt  = XT + ((size_t)b * 128 + i) * 32;
        const float* xfb = XF + (size_t)b * 2048;
        const float* w2 = P + P_W2;
        int d = lane & 31;
        float y = 0.f;
        #pragma unroll
        for (int c = 0; c < 32; c++) y = fmaf(w2[d * 32 + c], xt[c], y);
        float xfr[32];
        #pragma unroll
        for (int c = 0; c < 32; c++) xfr[c] = xfb[(size_t)lane * 32 + c];
        float sc0 = 0.f;
        #pragma unroll
        for (int c = 0; c < 32; c++) sc0 = fmaf(__shfl(y, c, 64), xfr[c], sc0);
        float mx = sc0;
        #pragma unroll
        for (int off = 1; off < 64; off <<= 1) mx = fmaxf(mx, __shfl_xor(mx, off, 64));
        float e = __expf(sc0 - mx);
        float sm = e;
        #pragma unroll
        for (int off = 1; off < 64; off <<= 1) sm += __shfl_xor(sm, off, 64);
        float a = e / sm;
        float v[32];
        #pragma unroll
        for (int c = 0; c < 32; c++) v[c] = a * xfr[c];
        #pragma unroll
        for (int off = 1; off < 64; off <<= 1) {
            #pragma unroll
            for (int c = 0; c < 32; c++) v[c] += __shfl_xor(v[c], off, 64);
        }
        if (lane == 0) {
            float* o = XTF + ((size_t)b * 128 + i) * 32;
            #pragma unroll
            for (int c = 0; c < 32; c++) o[c] = xt[c] + v[c];
        }
    }
}

// ---------------- K7: row-max + final FC (dtype-aware output) ----------------
__global__ __launch_bounds__(64) void k7_out(const float* __restrict__ P,
                                             const float* __restrict__ XFF,
                                             const float* __restrict__ XTF,
                                             void* __restrict__ outp) {
    __shared__ float node[64];
    int b = blockIdx.x, tid = threadIdx.x;
    if (tid < 32) {
        float m = -1e30f;
        for (int r = 0; r < 64; r++) m = fmaxf(m, XFF[((size_t)b * 64 + r) * 32 + tid]);
        node[tid] = m;
    } else {
        int c = tid - 32;
        float m = -1e30f;
        for (int r = 0; r < 128; r++) m = fmaxf(m, XTF[((size_t)b * 128 + r) * 32 + c]);
        node[tid] = m;
    }
    __syncthreads();
    if (tid < 2) {
        float z = P[P_FCB + tid];
        #pragma unroll
        for (int k = 0; k < 64; k++) z = fmaf(P[P_FCW + tid * 64 + k], node[k], z);
        int isb = (int)P[P_FLAG];
        if (isb) ((u16*)outp)[b * 2 + tid] = f2bf(z);
        else     ((float*)outp)[b * 2 + tid] = z;
    }
}

// ---------------- launch ----------------
extern "C" void kernel_launch(void* const* d_in, const int* in_sizes, int n_in,
                              void* d_out, int out_size, void* d_ws, size_t ws_size,
                              hipStream_t stream) {
    (void)in_sizes; (void)n_in; (void)out_size; (void)ws_size;
    float* W = (float*)d_ws;
    Ptrs ptrs;
    for (int i = 0; i < 39; i++) ptrs.p[i] = d_in[i];
    const void* x = d_in[0];
    float* P = W;
    u16* STC = (u16*)(W + WS_M);    // overlays M (dead after k3)
    u16* SFC = (u16*)(W + WS_XF);   // overlays XF..XFF (free until k5)

    k0_setup<<<1, 256, 0, stream>>>(ptrs, P);
    k1_conv_m<<<2048, 256, 0, stream>>>(x, P, W + WS_M);
    k2_softmax<<<128, 256, 0, stream>>>(W + WS_M, W + WS_FCATT);
    k3n<<<512, 256, 0, stream>>>(x, W + WS_M, P, W + WS_FCATT, W + WS_TCATT);
    k4a_scores<<<16 * 36 + 16 * 136, 256, 0, stream>>>(P, W + WS_FCATT, W + WS_TCATT, SFC, STC);
    k4b_soft<<<6144, 256, 0, stream>>>(P, W + WS_FCATT, W + WS_TCATT, SFC, STC,
                                       W + WS_FCGAT, W + WS_TCGAT);
    k5_pool<<<32, 256, 0, stream>>>(P, W + WS_FCGAT, W + WS_TCGAT, W + WS_XF, W + WS_XT);
    k6_fuse<<<768, 256, 0, stream>>>(P, W + WS_XF, W + WS_XT, W + WS_XFF, W + WS_XTF);
    k7_out<<<16, 64, 0, stream>>>(P, W + WS_XFF, W + WS_XTF, d_out);
}